// Round 13
// baseline (6102.997 us; speedup 1.0000x reference)
//
#include <hip/hip_runtime.h>
#include <stdint.h>

// ---------------------------------------------------------------------------
// LSTM-VAE persistent kernel, MI355X (gfx950).  B=128, T=512, I=L=64, H=512,
// 100 decoder steps.  fp32 in/out; bf16 MFMA internal.
//
// 128 WGs = 8 batch-groups(g) x 16 hidden-slices(s), block=512 (8 waves).
// Slice owns 32 hidden dims = 128 interleaved gate rows [i0,f0,g0,o0,...];
// W_hh slice in 64 VGPRs/lane as MFMA B-fragments. Decoder folds x_hat via
// W_comb = W_hh_dec + W_ih_dec@W_out; x_hat on wave 7 of slices 0-3.
//
// Round-21: WAVE-AUTONOMOUS steady loop -- zero barriers, zero LDS, zero
// publish funnel.  Synthesis of individually-proven parts:
//   * Block layout [128 blocks][16 rows][8B] (r18/r19: bank conflicts
//     4.1e7->1.1e7; block b = s*8+wv holds dims b*4+{0..3}).
//   * Per-wave coalesced publish (r19: ONE 16-lane 8B-contiguous 128B
//     store -> WRITE_SIZE 318->83MB, no RMW).
//   * Consume: each wave loads its own 16 A-fragments (32x 8B pieces,
//     1:1 with producer stores) via __hip_atomic_load(AGENT,relaxed) --
//     emits the same coherent sc0sc1 loads as asm, but the COMPILER owns
//     registers + waitcnt placement, so all 32 stay in flight and the
//     wait sinks to first use.  This avoids the r13/r15 killer (split
//     issue/wait across asm statements -> compiler copies in-flight dest
//     VGPRs -> corruption); precedent: the z-exchange has used AGENT
//     atomics green since r5.  Per-8B phase check; stale-piece-only
//     retries (hot x2 then s_sleep(1), r20 policy).
//   * Soundness: wave publishes R+1 only after validating ALL of R =>
//     transitively every wave consumed R-1 => depth-2 hbuf reuse safe;
//     skew <= 1 round; no livelock.  Round 513 (h_dec0) local via LDS
//     (one-shot, barrier'd); VAE keeps the r18 barrier'd stage.
//
// Phase protocol (r9..r20, HW-verified): |h|<=1 so bit14 of every bf16 is
// 0.  Round R writes buf[R&1] with bf16s XOR'd by phase(R)<<14; phase
// alternates per buffer reuse; a dword with matching phase bits is
// entirely round-R data (stores dword-atomic).  Round 513 skipped ->
// shifted decoder phase formula.  hbuf1 pre-filled 0x40.  launch_bounds
// (512,2) -> 256-VGPR budget (fits fr64+wfrag64+wof64+misc ~220).
// ---------------------------------------------------------------------------

typedef short short8 __attribute__((ext_vector_type(8)));
typedef float f32x4 __attribute__((ext_vector_type(4)));
typedef unsigned int u32x4 __attribute__((ext_vector_type(4)));
typedef unsigned int u32x2 __attribute__((ext_vector_type(2)));
typedef unsigned long long u64;

#define WS_FLAGS  0           // 8 g x 16 s x 128 B (z exchange only)
#define WS_HBUF0  16384       // 128 KB
#define WS_HBUF1  147456      // 128 KB
#define WS_Z      278528      // 32 KB fp32
#define WS_BCOMB  311296      // 8 KB fp32
#define WS_WCOMB  319488      // 2 MB bf16
#define WS_SEQB   2416640     // 8 MB bf16 seq
#define WS_END    10805248
#define WS_ZERO   WS_HBUF1    // memset flags + hbuf0 (h0 = 0, phase 0)
#define HB1_SIZE  131072      // hbuf1: fill 0x40 (bit14=1, != phase 0)

#define AL_HALF   8192        // shorts per LDS tile buffer (128 blk x 16 x 4)

static __device__ __forceinline__ float b2f(unsigned short u) {
    return __builtin_bit_cast(float, (unsigned int)u << 16);
}
static __device__ __forceinline__ unsigned short f2b(float f) {
    unsigned int u = __builtin_bit_cast(unsigned int, f);
    unsigned int r = u + 0x7FFFu + ((u >> 16) & 1u);  // RNE
    return (unsigned short)(r >> 16);
}
static __device__ __forceinline__ float sigm(float x)  { return 1.0f / (1.0f + __expf(-x)); }
static __device__ __forceinline__ float tanhx(float x) { return 1.0f - 2.0f / (__expf(2.0f * x) + 1.0f); }

static __device__ __forceinline__ short8 cvt8(const float* p) {
    const float4 a = ((const float4*)p)[0];
    const float4 b = ((const float4*)p)[1];
    short8 r;
    r[0] = (short)f2b(a.x); r[1] = (short)f2b(a.y);
    r[2] = (short)f2b(a.z); r[3] = (short)f2b(a.w);
    r[4] = (short)f2b(b.x); r[5] = (short)f2b(b.y);
    r[6] = (short)f2b(b.z); r[7] = (short)f2b(b.w);
    return r;
}

// phase(R): encoder/VAE rounds 0..512: (R>>1)&1.  Round 513 skipped (local
// h_dec0).  Decoder rounds 514..613 shifted so every buffer reuse still
// alternates (buf0: 512(0),514(1),516(0)..; buf1: 511(1),515(0),517(1)..).
static __device__ __forceinline__ uint32_t phase_of(uint32_t R) {
    return (R <= 512u) ? ((R >> 1) & 1u)
                       : ((((R - 513u) >> 1) & 1u) ^ 1u);
}

// --- coherent (LLC-served) monolithic asm pair (VAE stage only) -----------
static __device__ __forceinline__ void load2x16_cc(const void* p0, const void* p1,
                                                   u32x4& v0, u32x4& v1) {
    asm volatile("global_load_dwordx4 %0, %2, off sc0 sc1\n\t"
                 "global_load_dwordx4 %1, %3, off sc0 sc1\n\t"
                 "s_waitcnt vmcnt(0)"
                 : "=&v"(v0), "=&v"(v1) : "v"(p0), "v"(p1) : "memory");
}
static __device__ __forceinline__ void drain_vm() {
    asm volatile("s_waitcnt vmcnt(0)" ::: "memory");
}

// ---------------------------------------------------------------------------
// Prologue A: seq fp32 -> bf16
// ---------------------------------------------------------------------------
__global__ void __launch_bounds__(256)
seqcvt_kernel(const float* __restrict__ src, unsigned short* __restrict__ dst)
{
    int i = (blockIdx.x * 256 + threadIdx.x) * 4;
    float4 v = *(const float4*)(src + i);
    uint32_t lo = (uint32_t)f2b(v.x) | ((uint32_t)f2b(v.y) << 16);
    uint32_t hi = (uint32_t)f2b(v.z) | ((uint32_t)f2b(v.w) << 16);
    uint2 o; o.x = lo; o.y = hi;
    *(uint2*)(dst + i) = o;
}

// ---------------------------------------------------------------------------
// Prologue B: W_comb = W_hh_dec + W_ih_dec @ W_out (bf16 out), b_comb (fp32)
// ---------------------------------------------------------------------------
__global__ void __launch_bounds__(256)
wcomb_kernel(const float* __restrict__ Wih_d,
             const float* __restrict__ Whh_d,
             const float* __restrict__ Wout,
             const float* __restrict__ bih_d,
             const float* __restrict__ bhh_d,
             const float* __restrict__ bout,
             unsigned char* __restrict__ ws)
{
    __shared__ float Ash[64][64];
    __shared__ float Bsh[64][65];
    const int bid = blockIdx.x, t = threadIdx.x;
    const int gt0 = (bid >> 3) * 64, ht0 = (bid & 7) * 64;
    for (int j = 0; j < 16; ++j) {
        int idx = t + j * 256;
        int r = idx >> 6, c = idx & 63;
        Ash[r][c] = Wih_d[(size_t)(gt0 + r) * 64 + c];
        Bsh[r][c] = Wout[(size_t)r * 512 + ht0 + c];
    }
    __syncthreads();
    const int gl = t >> 2, hl0 = (t & 3) * 16;
    for (int hh = 0; hh < 16; ++hh) {
        float acc = 0.f;
        #pragma unroll
        for (int i = 0; i < 64; ++i) acc += Ash[gl][i] * Bsh[i][hl0 + hh];
        int g = gt0 + gl, h = ht0 + hl0 + hh;
        float v = Whh_d[(size_t)g * 512 + h] + acc;
        ((unsigned short*)(ws + WS_WCOMB))[(size_t)g * 512 + h] = f2b(v);
    }
    if ((bid & 7) == 0 && t < 64) {
        int g = gt0 + t;
        float acc = bih_d[g] + bhh_d[g];
        #pragma unroll
        for (int i = 0; i < 64; ++i) acc += bout[i] * Ash[t][i];
        ((float*)(ws + WS_BCOMB))[g] = acc;
    }
}

// ---------------------------------------------------------------------------
// Main persistent kernel
// ---------------------------------------------------------------------------
__global__ void __launch_bounds__(512, 2)
vae_persistent(const float* __restrict__ seq,
               const unsigned short* __restrict__ seqb,
               const float* __restrict__ eps,
               const float* __restrict__ Wih_e,
               const float* __restrict__ Whh_e,
               const float* __restrict__ bih_e,
               const float* __restrict__ bhh_e,
               const float* __restrict__ Wmean,
               const float* __restrict__ bmean,
               const float* __restrict__ Wlv,
               const float* __restrict__ blv,
               const float* __restrict__ Winit,
               const float* __restrict__ binit,
               const float* __restrict__ Whh_d,
               const float* __restrict__ bih_d,
               const float* __restrict__ bhh_d,
               const float* __restrict__ Wout,
               const float* __restrict__ bout,
               unsigned char* __restrict__ ws,
               float* __restrict__ out)
{
    __shared__ __align__(16) short Al[2 * AL_HALF];  // VAE stage / h_dec0 only
    __shared__ float fbuf[128];                      // mean/logvar scratch
    __shared__ float zl[16 * 64];                    // z tile (fp32)

    const int tid  = threadIdx.x;
    const int g    = blockIdx.x & 7;        // batch group
    const int s    = blockIdx.x >> 3;       // hidden slice
    const int b0   = g * 16;
    const int lane = tid & 63;
    const int wv   = tid >> 6;
    const int col  = lane & 15;
    const int q    = lane >> 4;
    const int nloc = wv * 16 + col;
    const int gt   = nloc & 3;              // 0=i,1=f,2=g,3=o
    const int grow = gt * 512 + s * 32 + (nloc >> 2);

    uint32_t* flags = (uint32_t*)(ws + WS_FLAGS) + (size_t)g * 512;  // z only
    unsigned char* hbuf0 = ws + WS_HBUF0;
    unsigned char* hbuf1 = ws + WS_HBUF1;
    uint32_t* zbuf = (uint32_t*)(ws + WS_Z);

    float cst[4] = {0.f, 0.f, 0.f, 0.f};

    // LDS fragment offsets (block layout) -- used only for decoder d==0.
    int aoff[16];
    #pragma unroll
    for (int kt = 0; kt < 16; ++kt)
        aoff[kt] = (kt * 8 + q * 2) * 64 + col * 4;
    // VAE staging indices (r18)
    const int stg_byte = (tid >> 2) * 128 + (tid & 3) * 32;
    const int stg_di   = (tid >> 2) * 8 + (tid & 3) * 2;

    // ---- per-wave direct fragment consume (32x 8B coherent pieces) -------
    // piece (kt,half): byte (kt*8+q*2+half)*128 + col*8 = kt*1024 +
    // half*128 + (q*256+col*8).  1:1 with one producer lane's 8B store.
    u64 pc[32];
    const int fb_off = q * 256 + col * 8;

    auto issue_loads = [&](uint32_t R) {
        const unsigned char* src = ((R & 1) ? hbuf1 : hbuf0)
                                   + (size_t)g * 16384 + fb_off;
        #pragma unroll
        for (int kt = 0; kt < 16; ++kt) {
            pc[2 * kt] = __hip_atomic_load(
                (const u64*)(src + kt * 1024),
                __ATOMIC_RELAXED, __HIP_MEMORY_SCOPE_AGENT);
            pc[2 * kt + 1] = __hip_atomic_load(
                (const u64*)(src + kt * 1024 + 128),
                __ATOMIC_RELAXED, __HIP_MEMORY_SCOPE_AGENT);
        }
    };

    auto finish_frags = [&](uint32_t R) {
        const unsigned char* src = ((R & 1) ? hbuf1 : hbuf0)
                                   + (size_t)g * 16384 + fb_off;
        const u64 pmask = 0x4000400040004000ull;
        const u64 want  = phase_of(R) ? pmask : 0ull;
        uint32_t tries = 0;
        for (;;) {
            uint32_t bad = 0;
            #pragma unroll
            for (int i = 0; i < 32; ++i)
                if (((pc[i] & pmask) ^ want) != 0) bad |= (1u << i);
            if (bad == 0) break;
            if (tries >= 2) __builtin_amdgcn_s_sleep(1);   // r20 policy
            ++tries;
            #pragma unroll
            for (int kt = 0; kt < 16; ++kt) {
                if (bad & (1u << (2 * kt)))
                    pc[2 * kt] = __hip_atomic_load(
                        (const u64*)(src + kt * 1024),
                        __ATOMIC_RELAXED, __HIP_MEMORY_SCOPE_AGENT);
                if (bad & (1u << (2 * kt + 1)))
                    pc[2 * kt + 1] = __hip_atomic_load(
                        (const u64*)(src + kt * 1024 + 128),
                        __ATOMIC_RELAXED, __HIP_MEMORY_SCOPE_AGENT);
            }
        }
        #pragma unroll
        for (int i = 0; i < 32; ++i) pc[i] ^= want;        // decode
    };

    auto mkfrag = [&](int kt) -> short8 {
        u32x4 w;
        w[0] = (uint32_t)pc[2 * kt];     w[1] = (uint32_t)(pc[2 * kt] >> 32);
        w[2] = (uint32_t)pc[2 * kt + 1]; w[3] = (uint32_t)(pc[2 * kt + 1] >> 32);
        return __builtin_bit_cast(short8, w);
    };
    auto ldsfrag = [&](const short* ab, int kt) -> short8 {
        uint2 lo = *(const uint2*)(ab + aoff[kt]);
        uint2 hi = *(const uint2*)(ab + aoff[kt] + 64);
        u32x4 w; w[0] = lo.x; w[1] = lo.y; w[2] = hi.x; w[3] = hi.y;
        return __builtin_bit_cast(short8, w);
    };

    // ---- VAE one-shot staged wait (r18, barrier'd, proven) ---------------
    auto wait_and_stage = [&](uint32_t R) {
        const unsigned char* src = ((R & 1) ? hbuf1 : hbuf0) + (size_t)g * 16384;
        const uint32_t pm = phase_of(R) ? 0x40004000u : 0u;
        const unsigned char* p0 = src + stg_byte;
        u32x4 v0, v1;
        uint32_t tries = 0;
        for (;;) {
            load2x16_cc(p0, p0 + 16, v0, v1);
            uint32_t bad = 0;
            #pragma unroll
            for (int i = 0; i < 4; ++i) {
                bad |= (v0[i] & 0x40004000u) ^ pm;
                bad |= (v1[i] & 0x40004000u) ^ pm;
            }
            if (bad == 0) break;
            if (tries >= 2) __builtin_amdgcn_s_sleep(1);
            ++tries;
        }
        #pragma unroll
        for (int i = 0; i < 4; ++i) { v0[i] ^= pm; v1[i] ^= pm; }
        u32x4* dst = (u32x4*)(Al + (R & 1) * AL_HALF);
        dst[stg_di]     = v0;
        dst[stg_di + 1] = v1;
        __syncthreads();
    };

    // ---- cell update + per-wave COALESCED publish (r19, proven) ----------
    auto cell_publish = [&](f32x4 acc, uint32_t R) {
        float act[4];
        #pragma unroll
        for (int r = 0; r < 4; ++r)
            act[r] = (gt == 2) ? tanhx(acc[r]) : sigm(acc[r]);
        int base = lane & ~3;
        #pragma unroll
        for (int r = 0; r < 4; ++r) {
            float vi = __shfl(act[r], base + 0);
            float vf = __shfl(act[r], base + 1);
            float vg = __shfl(act[r], base + 2);
            float vo = __shfl(act[r], base + 3);
            cst[r] = vf * cst[r] + vi * vg;
            act[r] = vo * tanhx(cst[r]);
        }
        unsigned char* dst = ((R & 1) ? hbuf1 : hbuf0) + (size_t)g * 16384
                             + (s * 8 + wv) * 128;
        const uint32_t pm = phase_of(R) ? 0x40004000u : 0u;
        const int qb = lane & 48;
        uint32_t pl0, ph0, pl1, ph1, pl2, ph2, pl3, ph3;
        {
            uint32_t u, g0, g1, g2, g3;
            u = (uint32_t)f2b(act[0]);
            g0 = (uint32_t)__shfl((int)u, qb + 0);  g1 = (uint32_t)__shfl((int)u, qb + 4);
            g2 = (uint32_t)__shfl((int)u, qb + 8);  g3 = (uint32_t)__shfl((int)u, qb + 12);
            pl0 = (g0 | (g1 << 16)) ^ pm;  ph0 = (g2 | (g3 << 16)) ^ pm;
            u = (uint32_t)f2b(act[1]);
            g0 = (uint32_t)__shfl((int)u, qb + 0);  g1 = (uint32_t)__shfl((int)u, qb + 4);
            g2 = (uint32_t)__shfl((int)u, qb + 8);  g3 = (uint32_t)__shfl((int)u, qb + 12);
            pl1 = (g0 | (g1 << 16)) ^ pm;  ph1 = (g2 | (g3 << 16)) ^ pm;
            u = (uint32_t)f2b(act[2]);
            g0 = (uint32_t)__shfl((int)u, qb + 0);  g1 = (uint32_t)__shfl((int)u, qb + 4);
            g2 = (uint32_t)__shfl((int)u, qb + 8);  g3 = (uint32_t)__shfl((int)u, qb + 12);
            pl2 = (g0 | (g1 << 16)) ^ pm;  ph2 = (g2 | (g3 << 16)) ^ pm;
            u = (uint32_t)f2b(act[3]);
            g0 = (uint32_t)__shfl((int)u, qb + 0);  g1 = (uint32_t)__shfl((int)u, qb + 4);
            g2 = (uint32_t)__shfl((int)u, qb + 8);  g3 = (uint32_t)__shfl((int)u, qb + 12);
            pl3 = (g0 | (g1 << 16)) ^ pm;  ph3 = (g2 | (g3 << 16)) ^ pm;
        }
        uint32_t lo = (col == 0) ? pl0 : (col == 1) ? pl1 : (col == 2) ? pl2 : pl3;
        uint32_t hi = (col == 0) ? ph0 : (col == 1) ? ph1 : (col == 2) ? ph2 : ph3;
        if (col < 4) {                         // 16 lanes, contiguous 128B
            u32x2 pk; pk[0] = lo; pk[1] = hi;
            void* p = dst + (q * 4 + col) * 8;
            asm volatile("global_store_dwordx2 %0, %1, off sc0 sc1"
                         :: "v"(p), "v"(pk) : "memory");
        }
    };

    short8 wfrag[16];
    auto load_wfrag_f32 = [&](const float* Wsrc) {
        #pragma unroll
        for (int kt = 0; kt < 16; ++kt)
            wfrag[kt] = cvt8(Wsrc + (size_t)grow * 512 + kt * 32 + q * 8);
    };
    auto load_wfrag_bf16 = [&](const unsigned short* Wsrc) {
        #pragma unroll
        for (int kt = 0; kt < 16; ++kt)
            wfrag[kt] = *(const short8*)((const short*)Wsrc +
                         (size_t)grow * 512 + kt * 32 + q * 8);
    };

    // ---------------- encoder: 512 steps (no barriers) ----------------
    load_wfrag_f32(Whh_e);
    short8 xwf[2];
    #pragma unroll
    for (int kt = 0; kt < 2; ++kt)
        xwf[kt] = cvt8(Wih_e + (size_t)grow * 64 + kt * 32 + q * 8);
    const float bias_e = bih_e[grow] + bhh_e[grow];

    auto load_x = [&](int t, short8* xf) {
        if (seqb) {
            const short* xs = (const short*)seqb + ((size_t)(b0 + col) * 512 + t) * 64 + q * 8;
            xf[0] = *(const short8*)(xs);
            xf[1] = *(const short8*)(xs + 32);
        } else {
            const float* xs = seq + ((size_t)(b0 + col) * 512 + t) * 64 + q * 8;
            xf[0] = cvt8(xs);
            xf[1] = cvt8(xs + 32);
        }
    };

    short8 xf[2];
    load_x(0, xf);
    for (uint32_t t = 0; t < 512; ++t) {
        issue_loads(t);                      // t=0: hbuf0 zeros, phase 0
        f32x4 acc = {bias_e, bias_e, bias_e, bias_e};
        acc = __builtin_amdgcn_mfma_f32_16x16x32_bf16(xf[0], xwf[0], acc, 0, 0, 0);
        acc = __builtin_amdgcn_mfma_f32_16x16x32_bf16(xf[1], xwf[1], acc, 0, 0, 0);
        if (t < 511) load_x(t + 1, xf);
        finish_frags(t);
        f32x4 acc1 = {0.f, 0.f, 0.f, 0.f};
        #pragma unroll
        for (int kt = 0; kt < 16; kt += 2) {
            acc  = __builtin_amdgcn_mfma_f32_16x16x32_bf16(mkfrag(kt),     wfrag[kt],     acc,  0, 0, 0);
            acc1 = __builtin_amdgcn_mfma_f32_16x16x32_bf16(mkfrag(kt + 1), wfrag[kt + 1], acc1, 0, 0, 0);
        }
        #pragma unroll
        for (int r = 0; r < 4; ++r) acc[r] += acc1[r];
        cell_publish(acc, t + 1);
    }

    // ---------------- VAE reparameterization (flag 513 = z ready) ---------
    wait_and_stage(512);                     // Al[0] = h_n (block layout)
    if (tid < 128) {
        int which = tid >> 6, idx = tid & 63;
        int b = idx >> 2, ldl = idx & 3;
        int ld = s * 4 + ldl;
        const float* wrow = (which ? Wlv : Wmean) + (size_t)ld * 512;
        float a = (which ? blv[ld] : bmean[ld]);
        for (int u = 0; u < 128; ++u) {
            const short* ap = Al + u * 64 + b * 4;
            const float* wp = wrow + u * 4;
            #pragma unroll
            for (int e = 0; e < 4; ++e)
                a += b2f((unsigned short)ap[e]) * wp[e];
        }
        out[819200 + which * 8192 + (size_t)(b0 + b) * 64 + ld] = a;
        fbuf[which * 64 + idx] = a;
    }
    __syncthreads();
    if (wv == 0) {
        int b = lane >> 2, ldl = lane & 3;
        int ld = s * 4 + ldl;
        float m = fbuf[lane], lv = fbuf[64 + lane];
        float e = eps[(size_t)(b0 + b) * 64 + ld];
        float z = m + e * __expf(0.5f * lv);
        __hip_atomic_store(zbuf + (size_t)(b0 + b) * 64 + ld,
                           __builtin_bit_cast(uint32_t, z),
                           __ATOMIC_RELAXED, __HIP_MEMORY_SCOPE_AGENT);
        drain_vm();
        if (lane == 0)
            __hip_atomic_store(&flags[s * 32], 513u,
                               __ATOMIC_RELAXED, __HIP_MEMORY_SCOPE_AGENT);
    }
    if (wv == 0 && lane < 16)
        while (__hip_atomic_load(&flags[lane * 32], __ATOMIC_RELAXED,
                                 __HIP_MEMORY_SCOPE_AGENT) < 513u) {}
    __syncthreads();

    // h_dec0 = z @ W_init^T + b_init -> Al[1] (round-513 parity, block layout)
    #pragma unroll
    for (int j = 0; j < 2; ++j) {
        int idx = tid + j * 512;
        int b = idx >> 6, l = idx & 63;
        uint32_t v = __hip_atomic_load(zbuf + (size_t)(b0 + b) * 64 + l,
                                       __ATOMIC_RELAXED, __HIP_MEMORY_SCOPE_AGENT);
        zl[b * 64 + l] = __builtin_bit_cast(float, v);
    }
    __syncthreads();
    {
        int b = tid >> 5, c = tid & 31;
        #pragma unroll
        for (int j = 0; j < 16; ++j) {
            int hd = c * 16 + j;
            float a = binit[hd];
            const float* wr = Winit + (size_t)hd * 64;
            #pragma unroll
            for (int l = 0; l < 64; ++l) a += zl[b * 64 + l] * wr[l];
            Al[AL_HALF + (hd >> 2) * 64 + b * 4 + (hd & 3)] = (short)f2b(a);
        }
    }
    #pragma unroll
    for (int r = 0; r < 4; ++r) cst[r] = 0.f;
    __syncthreads();

    // -------- decoder: 100 steps; step d publishes h_{d+1} as R=514+d -----
    short8 wof[16];
    float xbias = 0.f;
    const bool xw = (s < 4 && wv == 7);      // x_hat duty
    if (xw) {
        xbias = bout[s * 16 + col];
        #pragma unroll
        for (int kt = 0; kt < 16; ++kt)
            wof[kt] = cvt8(Wout + (size_t)(s * 16 + col) * 512 + kt * 32 + q * 8);
    }
    auto xhat_emit = [&](int d) {            // x_hat_d from pc (= h_{d+1})
        f32x4 a2 = {xbias, xbias, xbias, xbias};
        #pragma unroll
        for (int kt = 0; kt < 16; ++kt)
            a2 = __builtin_amdgcn_mfma_f32_16x16x32_bf16(mkfrag(kt), wof[kt], a2, 0, 0, 0);
        #pragma unroll
        for (int r = 0; r < 4; ++r) {
            int b = q * 4 + r;
            out[((size_t)(b0 + b) * 100 + d) * 64 + s * 16 + col] = a2[r];
        }
    };

    load_wfrag_f32(Whh_d);                   // step 0: x0 == 0
    float bias = bih_d[grow] + bhh_d[grow];
    for (uint32_t d = 0; d < 100; ++d) {
        f32x4 acc = {bias, bias, bias, bias};
        f32x4 acc1 = {0.f, 0.f, 0.f, 0.f};
        if (d == 0) {                        // h_dec0 from LDS (local)
            const short* ab = Al + AL_HALF;
            #pragma unroll
            for (int kt = 0; kt < 16; kt += 2) {
                acc  = __builtin_amdgcn_mfma_f32_16x16x32_bf16(ldsfrag(ab, kt),     wfrag[kt],     acc,  0, 0, 0);
                acc1 = __builtin_amdgcn_mfma_f32_16x16x32_bf16(ldsfrag(ab, kt + 1), wfrag[kt + 1], acc1, 0, 0, 0);
            }
        } else {
            issue_loads(513 + d);            // pc <- h_d (round 513+d)
            finish_frags(513 + d);
            #pragma unroll
            for (int kt = 0; kt < 16; kt += 2) {
                acc  = __builtin_amdgcn_mfma_f32_16x16x32_bf16(mkfrag(kt),     wfrag[kt],     acc,  0, 0, 0);
                acc1 = __builtin_amdgcn_mfma_f32_16x16x32_bf16(mkfrag(kt + 1), wfrag[kt + 1], acc1, 0, 0, 0);
            }
        }
        #pragma unroll
        for (int r = 0; r < 4; ++r) acc[r] += acc1[r];
        cell_publish(acc, 514 + d);
        if (d >= 1 && xw) xhat_emit(d - 1);  // pc holds h_d
        if (d == 0) {
            load_wfrag_bf16((const unsigned short*)(ws + WS_WCOMB));
            bias = ((const float*)(ws + WS_BCOMB))[grow];
        }
    }
    if (xw) {                                // pc <- h_100 (round 613)
        issue_loads(613);
        finish_frags(613);
        xhat_emit(99);
    }
}

extern "C" void kernel_launch(void* const* d_in, const int* in_sizes, int n_in,
                              void* d_out, int out_size, void* d_ws, size_t ws_size,
                              hipStream_t stream) {
    (void)in_sizes; (void)n_in; (void)out_size;
    const float* seq   = (const float*)d_in[0];
    const float* eps   = (const float*)d_in[2];
    const float* Wih_e = (const float*)d_in[3];
    const float* Whh_e = (const float*)d_in[4];
    const float* bih_e = (const float*)d_in[5];
    const float* bhh_e = (const float*)d_in[6];
    const float* Wmean = (const float*)d_in[7];
    const float* bmean = (const float*)d_in[8];
    const float* Wlv   = (const float*)d_in[9];
    const float* blv   = (const float*)d_in[10];
    const float* Winit = (const float*)d_in[11];
    const float* binit = (const float*)d_in[12];
    const float* Wih_d = (const float*)d_in[13];
    const float* Whh_d = (const float*)d_in[14];
    const float* bih_d = (const float*)d_in[15];
    const float* bhh_d = (const float*)d_in[16];
    const float* Wout  = (const float*)d_in[17];
    const float* bout  = (const float*)d_in[18];
    unsigned char* ws = (unsigned char*)d_ws;
    float* out = (float*)d_out;

    const bool have_seqb = ws_size >= (size_t)WS_END;
    unsigned short* seqb = have_seqb ? (unsigned short*)(ws + WS_SEQB) : nullptr;

    hipMemsetAsync(ws, 0, WS_ZERO, stream);            // flags + hbuf0 (phase 0)
    hipMemsetAsync(ws + WS_HBUF1, 0x40, HB1_SIZE, stream);  // hbuf1: bit14=1
    if (have_seqb)
        seqcvt_kernel<<<4096, 256, 0, stream>>>(seq, seqb);
    wcomb_kernel<<<256, 256, 0, stream>>>(Wih_d, Whh_d, Wout, bih_d, bhh_d, bout, ws);
    vae_persistent<<<128, 512, 0, stream>>>(
        seq, seqb, eps, Wih_e, Whh_e, bih_e, bhh_e,
        Wmean, bmean, Wlv, blv, Winit, binit,
        Whh_d, bih_d, bhh_d, Wout, bout, ws, out);
}